// Round 3
// baseline (211.810 us; speedup 1.0000x reference)
//
#include <hip/hip_runtime.h>

// GHM-C loss, one-pass:
//   q = (c==t) ? -p : p;  g = sigmoid(q);  bce = softplus(q)
//   bin = min(int(g*10), 9)
//   S[bin] += w*bce, cnt[bin] += 1 via fire-and-forget LDS atomics into
//   per-thread stripes (stride 11 -> single-writer, deterministic, 2-way max
//   bank aliasing = free). No RMW dependency chain.
//   loss = ( sum_b S[b] * (tot/cnt[b]) ) / n_nonempty / sum(w over N*C)

#define NROWS 4194304
#define NCLS 8
#define BINS 10

constexpr int BLOCK = 256;
constexpr int MAXGRID = 4096;
constexpr int STRIPE = 11; // 11 coprime 32 -> worst case 2 lanes/bank (free)

__global__ __launch_bounds__(BLOCK) void ghm_main(
    const float* __restrict__ pred, const int* __restrict__ target,
    const float* __restrict__ weight, float* __restrict__ wsF,
    unsigned int* __restrict__ wsU)
{
    __shared__ float        sS[BLOCK * STRIPE];
    __shared__ unsigned int sC[BLOCK * STRIPE];
    __shared__ float        wlds[NCLS];

    const int tid = threadIdx.x;
    if (tid < NCLS) wlds[tid] = weight[tid];
#pragma unroll
    for (int i = 0; i < BINS; ++i) {
        sS[tid * STRIPE + i] = 0.0f;
        sC[tid * STRIPE + i] = 0u;
    }
    __syncthreads();

    float* __restrict__        myS = &sS[tid * STRIPE];
    unsigned int* __restrict__ myC = &sC[tid * STRIPE];

    float sumw = 0.0f;
    const int stride = gridDim.x * BLOCK;
    const int gtid = blockIdx.x * BLOCK + tid;

    constexpr float NLOG2E = -1.4426950408889634f; // -log2(e)
    constexpr float LN2    = 0.6931471805599453f;

    for (int r = gtid; r < NROWS; r += stride) {
        const float4 p0 = reinterpret_cast<const float4*>(pred)[2 * r + 0];
        const float4 p1 = reinterpret_cast<const float4*>(pred)[2 * r + 1];
        const int   t  = target[r];
        const float w  = wlds[t];
        sumw += w;
        const float wln2 = w * LN2;
        const float pv[NCLS] = {p0.x, p0.y, p0.z, p0.w, p1.x, p1.y, p1.z, p1.w};
#pragma unroll
        for (int c = 0; c < NCLS; ++c) {
            const float p = pv[c];
            const float q = (c == t) ? -p : p;
            // e = exp(-|q|) via hardware v_exp_f32 (2^x); |q| folds as modifier
            const float e = __builtin_amdgcn_exp2f(NLOG2E * __builtin_fabsf(q));
            const float d = 1.0f + e;
            const float rr = __builtin_amdgcn_rcpf(d);
            const float g = (q >= 0.0f) ? rr : e * rr;      // sigmoid(q)
            const float l2 = __builtin_amdgcn_logf(d);      // log2(1+e)
            const float mq = fmaxf(q, 0.0f);
            const float v = fmaf(l2, wln2, w * mq);         // w * softplus(q)
            int b = (int)(g * 10.0f);
            b = (b > BINS - 1) ? (BINS - 1) : b;
            atomicAdd(&myS[b], v);   // ds_add_f32, no return, single writer
            atomicAdd(&myC[b], 1u);  // ds_add_u32
        }
    }

    sS[tid * STRIPE + BINS] = sumw;
    __syncthreads();

    // block tree-reduction across the 256 stripes (deterministic)
    for (int s = BLOCK / 2; s > 0; s >>= 1) {
        if (tid < s) {
#pragma unroll
            for (int i = 0; i < BINS; ++i) {
                sS[tid * STRIPE + i] += sS[(tid + s) * STRIPE + i];
                sC[tid * STRIPE + i] += sC[(tid + s) * STRIPE + i];
            }
            sS[tid * STRIPE + BINS] += sS[(tid + s) * STRIPE + BINS];
        }
        __syncthreads();
    }

    if (tid < BINS) {
        wsF[blockIdx.x * 32 + tid]      = sS[tid];
        wsU[blockIdx.x * 32 + 16 + tid] = sC[tid];
    }
    if (tid == BINS) wsF[blockIdx.x * 32 + BINS] = sS[BINS];
}

__global__ __launch_bounds__(BLOCK) void ghm_final(
    const float* __restrict__ wsF, const unsigned int* __restrict__ wsU,
    float* __restrict__ out, int nblocks)
{
    float S[BINS]; unsigned int cn[BINS]; float sw = 0.0f;
#pragma unroll
    for (int i = 0; i < BINS; ++i) { S[i] = 0.0f; cn[i] = 0u; }

    for (int b = threadIdx.x; b < nblocks; b += BLOCK) {
#pragma unroll
        for (int i = 0; i < BINS; ++i) {
            S[i]  += wsF[b * 32 + i];
            cn[i] += wsU[b * 32 + 16 + i];
        }
        sw += wsF[b * 32 + 10];
    }

#pragma unroll
    for (int i = 0; i < BINS; ++i) {
        float x = S[i]; unsigned int c2 = cn[i];
#pragma unroll
        for (int o = 32; o >= 1; o >>= 1) {
            x  += __shfl_xor(x, o, 64);
            c2 += __shfl_xor(c2, o, 64);
        }
        S[i] = x; cn[i] = c2;
    }
    {
        float x = sw;
#pragma unroll
        for (int o = 32; o >= 1; o >>= 1) x += __shfl_xor(x, o, 64);
        sw = x;
    }

    __shared__ float        lS[4][BINS + 1];
    __shared__ unsigned int lC[4][BINS];
    const int lane = threadIdx.x & 63;
    const int wv   = threadIdx.x >> 6;
    if (lane == 0) {
#pragma unroll
        for (int i = 0; i < BINS; ++i) { lS[wv][i] = S[i]; lC[wv][i] = cn[i]; }
        lS[wv][BINS] = sw;
    }
    __syncthreads();
    if (threadIdx.x == 0) {
        const float tot = 33554432.0f; // N*C
        int nne = 0; float acc = 0.0f;
        const float swt = lS[0][BINS] + lS[1][BINS] + lS[2][BINS] + lS[3][BINS];
#pragma unroll
        for (int i = 0; i < BINS; ++i) {
            const unsigned int c2 = lC[0][i] + lC[1][i] + lC[2][i] + lC[3][i];
            const float s = lS[0][i] + lS[1][i] + lS[2][i] + lS[3][i];
            if (c2 > 0u) { nne++; acc += s * (tot / (float)c2); }
        }
        out[0] = acc / (float)nne / (8.0f * swt);
    }
}

extern "C" void kernel_launch(void* const* d_in, const int* in_sizes, int n_in,
                              void* d_out, int out_size, void* d_ws, size_t ws_size,
                              hipStream_t stream) {
    const float* pred   = (const float*)d_in[0];
    const int*   target = (const int*)d_in[1];
    const float* weight = (const float*)d_in[2];
    float* out = (float*)d_out;

    int blocks = MAXGRID;
    const size_t need = (size_t)MAXGRID * 128u;
    if (ws_size < need) {
        int cap = (int)(ws_size / 128u);
        blocks = cap < 1 ? 1 : (cap > MAXGRID ? MAXGRID : cap);
    }

    ghm_main<<<blocks, BLOCK, 0, stream>>>(pred, target, weight,
                                           (float*)d_ws, (unsigned int*)d_ws);
    ghm_final<<<1, BLOCK, 0, stream>>>((const float*)d_ws, (const unsigned int*)d_ws,
                                       out, blocks);
}

// Round 4
// 55.999 us; speedup vs baseline: 3.7824x; 3.7824x over previous
//
#include <hip/hip_runtime.h>

// GHM-C loss, one-pass, register-only accumulation:
//   q = (c==t) ? -p : p ; e = exp(-|q|) ; bce = max(q,0) + ln(1+e)
//   bin thresholds on |q|: cthr = #{|q| < ln9, ln4, ln(7/3), ln(3/2)} (monotone)
//   bin = q>=0 ? 9-cthr : cthr
//   Prefix accumulators: sP_hi[i] = sum of w*bce over (q>=0 & cthr>=i), i=0..4
//   (likewise lo); counts via packed 6-bit 5-field LUT words. S[bin]/cnt[bin]
//   reconstructed by differencing in the final kernel.

#define NROWS 4194304
#define BINS 10

constexpr int BLOCK = 256;
constexpr int MAXGRID = 2048;
// ws per block: 32 floats: [0..4]=PhiPre, [5..9]=PloPre, [10]=sumw,
//                          [16..20]=cntHiPre, [21..25]=cntLoPre

__global__ __launch_bounds__(BLOCK) void ghm_main(
    const float* __restrict__ pred, const int* __restrict__ target,
    const float* __restrict__ weight, float* __restrict__ ws)
{
    __shared__ float wlds[8];
    const int tid = threadIdx.x;
    if (tid < 8) wlds[tid] = weight[tid];
    __syncthreads();

    float sP[10];      // [0..4] hi prefix sums, [5..9] lo prefix sums
#pragma unroll
    for (int i = 0; i < 10; ++i) sP[i] = 0.f;
    unsigned cP[10];   // flushed prefix counts
#pragma unroll
    for (int i = 0; i < 10; ++i) cP[i] = 0u;
    float sumw = 0.f;

    const int stride = gridDim.x * BLOCK;

    constexpr float NLOG2E = -1.4426950408889634f; // -log2(e)
    constexpr float LN2    = 0.6931471805599453f;
    constexpr float A0 = 2.1972245773362196f;  // ln 9
    constexpr float A1 = 1.3862943611198906f;  // ln 4
    constexpr float A2 = 0.8472978603872037f;  // ln(7/3)
    constexpr float A3 = 0.4054651081081644f;  // ln(3/2)
    const unsigned LUT0 = 0x1u, LUT1 = 0x41u, LUT2 = 0x1041u,
                   LUT3 = 0x41041u, LUT4 = 0x1041041u;

    for (int r = blockIdx.x * BLOCK + tid; r < NROWS; ) {
        unsigned aHi = 0u, aLo = 0u;   // 5 x 6-bit prefix-count fields
#pragma unroll
        for (int k = 0; k < 4; ++k, r += stride) {   // 32 elems <= 63/field
            const float4 p0 = reinterpret_cast<const float4*>(pred)[2 * r];
            const float4 p1 = reinterpret_cast<const float4*>(pred)[2 * r + 1];
            const int t = target[r];
            const float w = wlds[t];
            sumw += w;
            const float wln2 = w * LN2;
            const float pv[8] = {p0.x, p0.y, p0.z, p0.w, p1.x, p1.y, p1.z, p1.w};
#pragma unroll
            for (int c = 0; c < 8; ++c) {
                const float p = pv[c];
                const float q = (c == t) ? -p : p;
                const float aq = __builtin_fabsf(q);
                const float e = __builtin_amdgcn_exp2f(aq * NLOG2E); // exp(-|q|)
                const bool c0 = aq < A0, c1 = aq < A1, c2 = aq < A2, c3 = aq < A3;
                const bool qp = q >= 0.f;
                const float l = __builtin_amdgcn_logf(1.0f + e);     // log2(1+e)
                const float v = fmaf(l, wln2, w * fmaxf(q, 0.f));    // w*softplus(q)
                const float vhi = qp ? v : 0.f;
                const float vlo = v - vhi;
                sP[0] += vhi;               sP[5] += vlo;
                sP[1] += c0 ? vhi : 0.f;    sP[6] += c0 ? vlo : 0.f;
                sP[2] += c1 ? vhi : 0.f;    sP[7] += c1 ? vlo : 0.f;
                sP[3] += c2 ? vhi : 0.f;    sP[8] += c2 ? vlo : 0.f;
                sP[4] += c3 ? vhi : 0.f;    sP[9] += c3 ? vlo : 0.f;
                unsigned lut = c0 ? LUT1 : LUT0;  // LUT by cthr (monotone chain)
                lut = c1 ? LUT2 : lut;
                lut = c2 ? LUT3 : lut;
                lut = c3 ? LUT4 : lut;
                const unsigned ih = qp ? lut : 0u;
                aHi += ih;
                aLo += lut - ih;
            }
        }
#pragma unroll
        for (int i = 0; i < 5; ++i) {
            cP[i]     += (aHi >> (6 * i)) & 63u;
            cP[5 + i] += (aLo >> (6 * i)) & 63u;
        }
    }

    // wave reduction (10 floats, 10 u32s, sumw)
#pragma unroll
    for (int i = 0; i < 10; ++i) {
        float x = sP[i]; unsigned ci = cP[i];
#pragma unroll
        for (int o = 32; o >= 1; o >>= 1) {
            x  += __shfl_xor(x, o, 64);
            ci += __shfl_xor(ci, o, 64);
        }
        sP[i] = x; cP[i] = ci;
    }
    {
        float x = sumw;
#pragma unroll
        for (int o = 32; o >= 1; o >>= 1) x += __shfl_xor(x, o, 64);
        sumw = x;
    }

    __shared__ float red[4][21];
    const int lane = tid & 63, wv = tid >> 6;
    if (lane == 0) {
#pragma unroll
        for (int i = 0; i < 10; ++i) red[wv][i] = sP[i];
#pragma unroll
        for (int i = 0; i < 10; ++i) red[wv][10 + i] = (float)cP[i]; // <= 4096*8 exact
        red[wv][20] = sumw;
    }
    __syncthreads();
    if (tid < 21) {
        const float s = red[0][tid] + red[1][tid] + red[2][tid] + red[3][tid];
        const int slot = tid < 10 ? tid : (tid < 20 ? tid + 6 : 10);
        ws[blockIdx.x * 32 + slot] = s;
    }
}

__global__ __launch_bounds__(BLOCK) void ghm_final(
    const float* __restrict__ ws, float* __restrict__ out, int nblocks)
{
    float a21[21];
#pragma unroll
    for (int i = 0; i < 21; ++i) a21[i] = 0.f;

    for (int b = threadIdx.x; b < nblocks; b += BLOCK) {
#pragma unroll
        for (int i = 0; i < 10; ++i) a21[i] += ws[b * 32 + i];
#pragma unroll
        for (int i = 0; i < 10; ++i) a21[10 + i] += ws[b * 32 + 16 + i];
        a21[20] += ws[b * 32 + 10];
    }

#pragma unroll
    for (int i = 0; i < 21; ++i) {
        float x = a21[i];
#pragma unroll
        for (int o = 32; o >= 1; o >>= 1) x += __shfl_xor(x, o, 64);
        a21[i] = x;
    }

    __shared__ float red[4][21];
    const int tid = threadIdx.x;
    const int lane = tid & 63, wv = tid >> 6;
    if (lane == 0) {
#pragma unroll
        for (int i = 0; i < 21; ++i) red[wv][i] = a21[i];
    }
    __syncthreads();
    if (tid == 0) {
        float T[21];
#pragma unroll
        for (int i = 0; i < 21; ++i)
            T[i] = red[0][i] + red[1][i] + red[2][i] + red[3][i];
        // T[0..4]=PhiPre, T[5..9]=PloPre, T[10..14]=CntHiPre, T[15..19]=CntLoPre, T[20]=sumw
        float S[10], CN[10];
#pragma unroll
        for (int k = 0; k < 5; ++k) {
            const float shn = (k < 4) ? T[k + 1]      : 0.f;
            const float sln = (k < 4) ? T[5 + k + 1]  : 0.f;
            const float chn = (k < 4) ? T[10 + k + 1] : 0.f;
            const float cln = (k < 4) ? T[15 + k + 1] : 0.f;
            S[9 - k]  = T[k]      - shn;  CN[9 - k] = T[10 + k] - chn;
            S[k]      = T[5 + k]  - sln;  CN[k]     = T[15 + k] - cln;
        }
        int nne = 0; float acc = 0.f;
        const float tot = 33554432.0f; // N*C
#pragma unroll
        for (int i = 0; i < 10; ++i) {
            if (CN[i] > 0.5f) { nne++; acc += S[i] * (tot / CN[i]); }
        }
        out[0] = acc / (float)nne / (8.0f * T[20]);
    }
}

extern "C" void kernel_launch(void* const* d_in, const int* in_sizes, int n_in,
                              void* d_out, int out_size, void* d_ws, size_t ws_size,
                              hipStream_t stream) {
    const float* pred   = (const float*)d_in[0];
    const int*   target = (const int*)d_in[1];
    const float* weight = (const float*)d_in[2];
    float* out = (float*)d_out;

    int blocks = MAXGRID;
    if (ws_size < (size_t)MAXGRID * 128u) {
        const int cap = (int)(ws_size / 128u);
        blocks = 1;
        while (blocks * 2 <= cap && blocks * 2 < MAXGRID) blocks *= 2; // pow2: exact divisibility
    }

    ghm_main<<<blocks, BLOCK, 0, stream>>>(pred, target, weight, (float*)d_ws);
    ghm_final<<<1, BLOCK, 0, stream>>>((const float*)d_ws, out, blocks);
}